// Round 3
// baseline (129.667 us; speedup 1.0000x reference)
//
#include <hip/hip_runtime.h>
#include <cmath>

typedef unsigned short u16;
typedef __attribute__((ext_vector_type(8))) short s8v;   // 8 bf16 payload (4 VGPRs)
typedef __attribute__((ext_vector_type(4))) float f4v;   // MFMA accumulator

__device__ __forceinline__ u16 f2bf(float f) {
    union { float f; unsigned u; } v; v.f = f;
    unsigned r = v.u + 0x7FFFu + ((v.u >> 16) & 1u);   // RNE
    return (u16)(r >> 16);
}
__device__ __forceinline__ float bf2f(u16 h) {
    union { unsigned u; float f; } v; v.u = ((unsigned)h) << 16;
    return v.f;
}

// async global->LDS, 16B per lane, dest = wave-uniform base + lane*16
__device__ __forceinline__ void gload_lds16(const u16* g, u16* l) {
    __builtin_amdgcn_global_load_lds(
        (const __attribute__((address_space(1))) void*)g,
        (__attribute__((address_space(3))) void*)l,
        16, 0, 0);
}

// ---------------------------------------------------------------------------
// prep: W2T[n][k] = bf16(W2[k][n]);  VT[q][p] = bf16(W2[p][q] * U[q][p]),
//       U[q][p] = sum_i W3[q][i] * W1[i][p].   Also zero trJ.
// ---------------------------------------------------------------------------
__launch_bounds__(256)
__global__ void cnf_prep(const float* __restrict__ W1, const float* __restrict__ W2,
                         const float* __restrict__ W3,
                         u16* __restrict__ W2T, u16* __restrict__ VT,
                         float* __restrict__ trJ)
{
    __shared__ float w2s[32][33];
    const int a = blockIdx.x * 32;   // k / p base (rows of W2)
    const int b = blockIdx.y * 32;   // n / q base (cols of W2)
    const int t = threadIdx.x;
    #pragma unroll
    for (int it = 0; it < 4; ++it) {
        int idx = t + it * 256;
        int r = idx >> 5, c = idx & 31;
        w2s[r][c] = W2[(a + r) * 1024 + (b + c)];
    }
    __syncthreads();
    #pragma unroll
    for (int it = 0; it < 4; ++it) {
        int idx = t + it * 256;
        int rr = idx >> 5, cc = idx & 31;
        W2T[(b + rr) * 1024 + (a + cc)] = f2bf(w2s[cc][rr]);
    }
    #pragma unroll
    for (int it = 0; it < 4; ++it) {
        int idx = t + it * 256;
        int qq = idx >> 5, pp = idx & 31;
        float u = 0.f;
        const float* w3row = W3 + (b + qq) * 64;
        const float* w1col = W1 + (a + pp);
        #pragma unroll 8
        for (int i = 0; i < 64; ++i) u += w3row[i] * w1col[i * 1024];
        VT[(b + qq) * 1024 + (a + pp)] = f2bf(w2s[pp][qq] * u);
    }
    if (blockIdx.y == 0 && t < 128) trJ[blockIdx.x * 128 + t] = 0.f;
}

// ---------------------------------------------------------------------------
// gemm1: h1 = tanh(x_in @ W1 + b1), g1 = 1 - h1^2   (K=64, fp32 vector ALU)
// ---------------------------------------------------------------------------
__launch_bounds__(256)
__global__ void cnf_gemm1(const float* __restrict__ x, const float* __restrict__ W1,
                          const float* __restrict__ b1,
                          u16* __restrict__ h1, u16* __restrict__ g1)
{
    __shared__ float xs[8][64];
    const int t = threadIdx.x;
    const int b0 = (blockIdx.x >> 2) * 8;
    const int jt = blockIdx.x & 3;
    #pragma unroll
    for (int it = 0; it < 2; ++it) {
        int idx = t + it * 256;
        int row = idx >> 6, i = idx & 63;
        xs[row][i] = x[(b0 + row) * 65 + 1 + i];
    }
    __syncthreads();
    const int j = jt * 256 + t;
    float acc[8] = {0.f,0.f,0.f,0.f,0.f,0.f,0.f,0.f};
    #pragma unroll 8
    for (int i = 0; i < 64; ++i) {
        float w = W1[i * 1024 + j];
        #pragma unroll
        for (int r = 0; r < 8; ++r) acc[r] += xs[r][i] * w;
    }
    const float bv = b1[j];
    #pragma unroll
    for (int r = 0; r < 8; ++r) {
        float h = tanhf(acc[r] + bv);
        float gg = 1.f - h * h;
        h1[(b0 + r) * 1024 + j] = f2bf(h);
        g1[(b0 + r) * 1024 + j] = f2bf(gg);
    }
}

// ---------------------------------------------------------------------------
// mid: fused dual GEMM over K=1024 (tile 128x64, BK=32, 4 waves 2x2):
//   C2 = h1 @ W2   -> h2 = tanh(C2+b2) (bf16), g2 = 1-h2^2 (in reg)
//   T  = g1 @ V    -> trJ[row] += sum_col T*g2
// Staging: global_load_lds width=16 into FRAGMENT-LINEAR LDS (lane l's 16B at
// base+l*16, source pre-swizzled: row=lr, k=g*8) -> conflict-free ds_read_b128.
// Pipeline: 3 LDS buffers, stage tile t+2 while computing t; counted
// s_waitcnt vmcnt(6) (drains only tile t+1) + one raw s_barrier per K-step.
// Per-buffer layout (u16): [A1:8][A2:8][B1:4][B2:4] subtiles x 512 = 12288.
// ---------------------------------------------------------------------------
__launch_bounds__(256)
__global__ void cnf_mid(const u16* __restrict__ h1, const u16* __restrict__ g1,
                        const u16* __restrict__ W2T, const u16* __restrict__ VT,
                        const float* __restrict__ b2,
                        u16* __restrict__ h2, float* __restrict__ trJ)
{
    __shared__ __align__(16) u16 lds[3 * 12288];   // 72 KiB

    const int t = threadIdx.x;
    const int wave = t >> 6, lane = t & 63;
    const int wm = wave >> 1, wn = wave & 1;
    const int g = lane >> 4, lr = lane & 15;
    const int arow0 = blockIdx.x * 128;
    const int bcol0 = blockIdx.y * 64;

    // per-wave staging sources: 6 subtiles out of the flat list
    // T 0..7 -> A1 (h1), 8..15 -> A2 (g1), 16..19 -> B1 (W2T), 20..23 -> B2 (VT)
    const u16* sb[6];
    #pragma unroll
    for (int i = 0; i < 6; ++i) {
        const int T = wave * 6 + i;
        const u16* p;
        if (T < 8)       p = h1  + (size_t)(arow0 + T * 16 + lr) * 1024;
        else if (T < 16) p = g1  + (size_t)(arow0 + (T - 8) * 16 + lr) * 1024;
        else if (T < 20) p = W2T + (size_t)(bcol0 + (T - 16) * 16 + lr) * 1024;
        else             p = VT  + (size_t)(bcol0 + (T - 20) * 16 + lr) * 1024;
        sb[i] = p + g * 8;
    }
    u16* const dst0 = lds + wave * 6 * 512;   // wave-uniform dest base

    f4v acc1[4][2], acc2[4][2];
    #pragma unroll
    for (int mi = 0; mi < 4; ++mi)
        #pragma unroll
        for (int ni = 0; ni < 2; ++ni) {
            acc1[mi][ni] = f4v{0.f, 0.f, 0.f, 0.f};
            acc2[mi][ni] = f4v{0.f, 0.f, 0.f, 0.f};
        }

#define STAGE(tt, bb) do {                                        \
        u16* _d = dst0 + (bb) * 12288;                            \
        const int _k = (tt) * 32;                                 \
        _Pragma("unroll")                                         \
        for (int _i = 0; _i < 6; ++_i)                            \
            gload_lds16(sb[_i] + _k, _d + _i * 512);              \
    } while (0)

    STAGE(0, 0);
    STAGE(1, 1);
    asm volatile("s_waitcnt vmcnt(6)" ::: "memory");   // tile 0 landed
    __builtin_amdgcn_s_barrier();

    int cur = 0, nx = 2;
    const int lo = lane * 8;
    for (int kt = 0; kt < 32; ++kt) {
        if (kt < 30) STAGE(kt + 2, nx);

        u16* buf = lds + cur * 12288;
        s8v af1[4], af2[4], bf1[2], bf2[2];
        #pragma unroll
        for (int mi = 0; mi < 4; ++mi) {
            af1[mi] = *(const s8v*)(buf + (wm * 4 + mi) * 512 + lo);
            af2[mi] = *(const s8v*)(buf + (8 + wm * 4 + mi) * 512 + lo);
        }
        #pragma unroll
        for (int ni = 0; ni < 2; ++ni) {
            bf1[ni] = *(const s8v*)(buf + (16 + wn * 2 + ni) * 512 + lo);
            bf2[ni] = *(const s8v*)(buf + (20 + wn * 2 + ni) * 512 + lo);
        }
        #pragma unroll
        for (int mi = 0; mi < 4; ++mi)
            #pragma unroll
            for (int ni = 0; ni < 2; ++ni) {
                acc1[mi][ni] = __builtin_amdgcn_mfma_f32_16x16x32_bf16(af1[mi], bf1[ni], acc1[mi][ni], 0, 0, 0);
                acc2[mi][ni] = __builtin_amdgcn_mfma_f32_16x16x32_bf16(af2[mi], bf2[ni], acc2[mi][ni], 0, 0, 0);
            }

        if (kt < 30)       asm volatile("s_waitcnt vmcnt(6)" ::: "memory");
        else if (kt == 30) asm volatile("s_waitcnt vmcnt(0)" ::: "memory");
        if (kt < 31) __builtin_amdgcn_s_barrier();
        cur = (cur == 2) ? 0 : cur + 1;
        nx  = (nx == 2) ? 0 : nx + 1;
    }
#undef STAGE

    // epilogue: h2/g2 + trace partial reduction
    #pragma unroll
    for (int mi = 0; mi < 4; ++mi) {
        const int rowb = arow0 + wm * 64 + mi * 16 + g * 4;
        float vs[4] = {0.f, 0.f, 0.f, 0.f};
        #pragma unroll
        for (int ni = 0; ni < 2; ++ni) {
            const int col = bcol0 + wn * 32 + ni * 16 + lr;
            const float bv = b2[col];
            #pragma unroll
            for (int r = 0; r < 4; ++r) {
                float a2 = acc1[mi][ni][r] + bv;
                float hh = tanhf(a2);
                float gg = 1.f - hh * hh;
                h2[(rowb + r) * 1024 + col] = f2bf(hh);
                vs[r] += acc2[mi][ni][r] * gg;
            }
        }
        #pragma unroll
        for (int off = 1; off < 16; off <<= 1)
            #pragma unroll
            for (int r = 0; r < 4; ++r)
                vs[r] += __shfl_xor(vs[r], off);
        if (lr == 0) {
            #pragma unroll
            for (int r = 0; r < 4; ++r)
                atomicAdd(&trJ[rowb + r], vs[r]);
        }
    }
}

// ---------------------------------------------------------------------------
// out: y = h2 @ W3 + b3 -> out[:,1:65];  out[:,0] = -trJ
// ---------------------------------------------------------------------------
__launch_bounds__(256)
__global__ void cnf_out(const u16* __restrict__ h2, const float* __restrict__ W3,
                        const float* __restrict__ b3, const float* __restrict__ trJ,
                        float* __restrict__ out)
{
    __shared__ __align__(16) u16 hs[8][1024];
    __shared__ float red[4][8][64];
    const int t = threadIdx.x;
    const int b0 = blockIdx.x * 8;
    #pragma unroll
    for (int it = 0; it < 4; ++it) {
        int idx = t + it * 256;
        int row = idx >> 7, ch = idx & 127;
        *(s8v*)&hs[row][ch * 8] = *(const s8v*)&h2[(b0 + row) * 1024 + ch * 8];
    }
    __syncthreads();
    const int c = t & 63, s = t >> 6;
    float acc[8] = {0.f,0.f,0.f,0.f,0.f,0.f,0.f,0.f};
    for (int k = s * 256; k < s * 256 + 256; ++k) {
        float w = W3[k * 64 + c];
        #pragma unroll
        for (int r = 0; r < 8; ++r) acc[r] += bf2f(hs[r][k]) * w;
    }
    #pragma unroll
    for (int r = 0; r < 8; ++r) red[s][r][c] = acc[r];
    __syncthreads();
    for (int o = t; o < 512; o += 256) {
        int r = o >> 6, cc = o & 63;
        float sum = red[0][r][cc] + red[1][r][cc] + red[2][r][cc] + red[3][r][cc] + b3[cc];
        out[(b0 + r) * 65 + 1 + cc] = sum;
    }
    if (t < 8) out[(b0 + t) * 65] = -trJ[b0 + t];
}

// ---------------------------------------------------------------------------
extern "C" void kernel_launch(void* const* d_in, const int* in_sizes, int n_in,
                              void* d_out, int out_size, void* d_ws, size_t ws_size,
                              hipStream_t stream) {
    const float* x  = (const float*)d_in[0];
    const float* W1 = (const float*)d_in[1];
    const float* b1 = (const float*)d_in[2];
    const float* W2 = (const float*)d_in[3];
    const float* b2 = (const float*)d_in[4];
    const float* W3 = (const float*)d_in[5];
    const float* b3 = (const float*)d_in[6];
    float* out = (float*)d_out;

    char* ws = (char*)d_ws;
    u16*   h1b = (u16*)(ws);                       //  8 MB  (4096x1024 bf16)
    u16*   g1b = (u16*)(ws + (size_t)( 8u << 20)); //  8 MB
    u16*   h2b = (u16*)(ws + (size_t)(16u << 20)); //  8 MB
    u16*   W2T = (u16*)(ws + (size_t)(24u << 20)); //  2 MB  (1024x1024 bf16, n-major)
    u16*   VTb = (u16*)(ws + (size_t)(26u << 20)); //  2 MB
    float* trJ = (float*)(ws + (size_t)(28u << 20)); // 16 KB

    cnf_prep <<<dim3(32, 32), 256, 0, stream>>>(W1, W2, W3, W2T, VTb, trJ);
    cnf_gemm1<<<2048,         256, 0, stream>>>(x, W1, b1, h1b, g1b);
    cnf_mid  <<<dim3(32, 16), 256, 0, stream>>>(h1b, g1b, W2T, VTb, b2, h2b, trJ);
    cnf_out  <<<512,          256, 0, stream>>>(h2b, W3, b3, trJ, out);
}

// Round 4
// 113.952 us; speedup vs baseline: 1.1379x; 1.1379x over previous
//
#include <hip/hip_runtime.h>
#include <cmath>

typedef unsigned short u16;
typedef __attribute__((ext_vector_type(8))) short s8v;   // 8 bf16 payload (4 VGPRs)
typedef __attribute__((ext_vector_type(4))) float f4v;   // MFMA accumulator

__device__ __forceinline__ u16 f2bf(float f) {
    union { float f; unsigned u; } v; v.f = f;
    unsigned r = v.u + 0x7FFFu + ((v.u >> 16) & 1u);   // RNE
    return (u16)(r >> 16);
}
__device__ __forceinline__ float bf2f(u16 h) {
    union { unsigned u; float f; } v; v.u = ((unsigned)h) << 16;
    return v.f;
}
// fast tanh: 1 - 2/(1+exp2(2x*log2e)); |err| ~1e-6, saturates correctly
__device__ __forceinline__ float tanh_fast(float x) {
    float e = __builtin_amdgcn_exp2f(x * 2.88539008177792681f);
    return 1.f - 2.f * __builtin_amdgcn_rcpf(1.f + e);
}

// ---------------------------------------------------------------------------
// prep: W2T[n][k] = bf16(W2[k][n]);  VT[q][p] = bf16(W2[p][q] * U[q][p]),
//       U[q][p] = sum_i W3[q][i] * W1[i][p].   Also zero trJ.
// ---------------------------------------------------------------------------
__launch_bounds__(256)
__global__ void cnf_prep(const float* __restrict__ W1, const float* __restrict__ W2,
                         const float* __restrict__ W3,
                         u16* __restrict__ W2T, u16* __restrict__ VT,
                         float* __restrict__ trJ)
{
    __shared__ float w2s[32][33];
    const int a = blockIdx.x * 32;   // k / p base (rows of W2)
    const int b = blockIdx.y * 32;   // n / q base (cols of W2)
    const int t = threadIdx.x;
    #pragma unroll
    for (int it = 0; it < 4; ++it) {
        int idx = t + it * 256;
        int r = idx >> 5, c = idx & 31;
        w2s[r][c] = W2[(a + r) * 1024 + (b + c)];
    }
    __syncthreads();
    #pragma unroll
    for (int it = 0; it < 4; ++it) {
        int idx = t + it * 256;
        int rr = idx >> 5, cc = idx & 31;
        W2T[(b + rr) * 1024 + (a + cc)] = f2bf(w2s[cc][rr]);
    }
    #pragma unroll
    for (int it = 0; it < 4; ++it) {
        int idx = t + it * 256;
        int qq = idx >> 5, pp = idx & 31;
        float u = 0.f;
        const float* w3row = W3 + (b + qq) * 64;
        const float* w1col = W1 + (a + pp);
        #pragma unroll 8
        for (int i = 0; i < 64; ++i) u += w3row[i] * w1col[i * 1024];
        VT[(b + qq) * 1024 + (a + pp)] = f2bf(w2s[pp][qq] * u);
    }
    if (blockIdx.y == 0 && t < 128) trJ[blockIdx.x * 128 + t] = 0.f;
}

// ---------------------------------------------------------------------------
// gemm1: h1 = tanh(x_in @ W1 + b1), g1 = 1 - h1^2   (K=64, fp32 vector ALU)
// ---------------------------------------------------------------------------
__launch_bounds__(256)
__global__ void cnf_gemm1(const float* __restrict__ x, const float* __restrict__ W1,
                          const float* __restrict__ b1,
                          u16* __restrict__ h1, u16* __restrict__ g1)
{
    __shared__ float xs[8][64];
    const int t = threadIdx.x;
    const int b0 = (blockIdx.x >> 2) * 8;
    const int jt = blockIdx.x & 3;
    #pragma unroll
    for (int it = 0; it < 2; ++it) {
        int idx = t + it * 256;
        int row = idx >> 6, i = idx & 63;
        xs[row][i] = x[(b0 + row) * 65 + 1 + i];
    }
    __syncthreads();
    const int j = jt * 256 + t;
    float acc[8] = {0.f,0.f,0.f,0.f,0.f,0.f,0.f,0.f};
    #pragma unroll 8
    for (int i = 0; i < 64; ++i) {
        float w = W1[i * 1024 + j];
        #pragma unroll
        for (int r = 0; r < 8; ++r) acc[r] += xs[r][i] * w;
    }
    const float bv = b1[j];
    #pragma unroll
    for (int r = 0; r < 8; ++r) {
        float h = tanh_fast(acc[r] + bv);
        float gg = 1.f - h * h;
        h1[(b0 + r) * 1024 + j] = f2bf(h);
        g1[(b0 + r) * 1024 + j] = f2bf(gg);
    }
}

// ---------------------------------------------------------------------------
// mid: fused dual GEMM over K=1024 (tile 128x64, BK=32, 4 waves 2x2):
//   C2 = h1 @ W2   -> h2 = tanh(C2+b2) (bf16), g2 = 1-h2^2 (in reg)
//   T  = g1 @ V    -> trJ[row] += sum_col T*g2
// R2 structure (reg-staged, single LDS buffer, 2 barriers/K-step) with:
//  - fragment-linear LDS: 24 subtiles (16 rows x 32 k) of 64 16B slots,
//    slot u' = u ^ ((u>>4)<<2)  (XOR involution, applied on write AND read)
//    -> ds_write_b128 and ds_read_b128 both bank-conflict-free.
//  - T14 async-STAGE: iteration t+1's global loads issued before iteration
//    t's ds_writes (explicit register double-buffer).
// Subtiles: 0..7 = A1 (h1 rows), 8..15 = A2 (g1), 16..19 = B1 (W2T),
//           20..23 = B2 (VT). 24 x 512 u16 = 24 KiB.
// ---------------------------------------------------------------------------
__launch_bounds__(256)
__global__ void cnf_mid(const u16* __restrict__ h1, const u16* __restrict__ g1,
                        const u16* __restrict__ W2T, const u16* __restrict__ VT,
                        const float* __restrict__ b2,
                        u16* __restrict__ h2, float* __restrict__ trJ)
{
    __shared__ __align__(16) u16 lds[24 * 512];   // 24 KiB

    const int t = threadIdx.x;
    const int wave = t >> 6, lane = t & 63;
    const int wm = wave >> 1, wn = wave & 1;
    const int g = lane >> 4, lr = lane & 15;
    const int arow0 = blockIdx.x * 128;
    const int bcol0 = blockIdx.y * 64;

    // ---- staging geometry (per thread, invariant over K) ----
    const int srow = t >> 2;            // 0..63
    const int kc   = t & 3;             // k-chunk 0..3
    const int sch  = kc * 8;            // k offset within 32
    const int st   = srow >> 4;         // subtile row-group 0..3
    const int uw   = ((kc << 4) | (srow & 15)) ^ (kc << 2);  // swizzled slot
    const int doff = uw * 8;            // u16 offset within subtile

    const u16* sp[6];
    int dst[6];
    sp[0] = h1  + (size_t)(arow0 + srow) * 1024 + sch;       dst[0] = (st)      * 512 + doff;
    sp[1] = h1  + (size_t)(arow0 + 64 + srow) * 1024 + sch;  dst[1] = (4 + st)  * 512 + doff;
    sp[2] = g1  + (size_t)(arow0 + srow) * 1024 + sch;       dst[2] = (8 + st)  * 512 + doff;
    sp[3] = g1  + (size_t)(arow0 + 64 + srow) * 1024 + sch;  dst[3] = (12 + st) * 512 + doff;
    sp[4] = W2T + (size_t)(bcol0 + srow) * 1024 + sch;       dst[4] = (16 + st) * 512 + doff;
    sp[5] = VT  + (size_t)(bcol0 + srow) * 1024 + sch;       dst[5] = (20 + st) * 512 + doff;

    // ---- fragment read offset (swizzled, lane-linear) ----
    const int lo = (lane ^ ((lane >> 4) << 2)) * 8;   // u16 units within subtile

    f4v acc1[4][2], acc2[4][2];
    #pragma unroll
    for (int mi = 0; mi < 4; ++mi)
        #pragma unroll
        for (int ni = 0; ni < 2; ++ni) {
            acc1[mi][ni] = f4v{0.f, 0.f, 0.f, 0.f};
            acc2[mi][ni] = f4v{0.f, 0.f, 0.f, 0.f};
        }

    s8v ra0, ra1, ra2, ra3, ra4, ra5;
    ra0 = *(const s8v*)sp[0]; ra1 = *(const s8v*)sp[1];
    ra2 = *(const s8v*)sp[2]; ra3 = *(const s8v*)sp[3];
    ra4 = *(const s8v*)sp[4]; ra5 = *(const s8v*)sp[5];

    for (int kt = 0; kt < 32; ++kt) {
        // T14: issue next tile's global loads BEFORE this tile's LDS writes
        s8v rb0, rb1, rb2, rb3, rb4, rb5;
        if (kt < 31) {
            const int ko = (kt + 1) * 32;
            rb0 = *(const s8v*)(sp[0] + ko); rb1 = *(const s8v*)(sp[1] + ko);
            rb2 = *(const s8v*)(sp[2] + ko); rb3 = *(const s8v*)(sp[3] + ko);
            rb4 = *(const s8v*)(sp[4] + ko); rb5 = *(const s8v*)(sp[5] + ko);
        }
        *(s8v*)&lds[dst[0]] = ra0; *(s8v*)&lds[dst[1]] = ra1;
        *(s8v*)&lds[dst[2]] = ra2; *(s8v*)&lds[dst[3]] = ra3;
        *(s8v*)&lds[dst[4]] = ra4; *(s8v*)&lds[dst[5]] = ra5;
        __syncthreads();

        s8v af1[4], af2[4], bf1[2], bf2[2];
        #pragma unroll
        for (int mi = 0; mi < 4; ++mi) {
            af1[mi] = *(const s8v*)&lds[(wm * 4 + mi) * 512 + lo];
            af2[mi] = *(const s8v*)&lds[(8 + wm * 4 + mi) * 512 + lo];
        }
        #pragma unroll
        for (int ni = 0; ni < 2; ++ni) {
            bf1[ni] = *(const s8v*)&lds[(16 + wn * 2 + ni) * 512 + lo];
            bf2[ni] = *(const s8v*)&lds[(20 + wn * 2 + ni) * 512 + lo];
        }
        #pragma unroll
        for (int mi = 0; mi < 4; ++mi)
            #pragma unroll
            for (int ni = 0; ni < 2; ++ni) {
                acc1[mi][ni] = __builtin_amdgcn_mfma_f32_16x16x32_bf16(af1[mi], bf1[ni], acc1[mi][ni], 0, 0, 0);
                acc2[mi][ni] = __builtin_amdgcn_mfma_f32_16x16x32_bf16(af2[mi], bf2[ni], acc2[mi][ni], 0, 0, 0);
            }
        __syncthreads();

        if (kt < 31) {
            ra0 = rb0; ra1 = rb1; ra2 = rb2;
            ra3 = rb3; ra4 = rb4; ra5 = rb5;
        }
    }

    // epilogue: h2/g2 + trace partial reduction
    #pragma unroll
    for (int mi = 0; mi < 4; ++mi) {
        const int rowb = arow0 + wm * 64 + mi * 16 + g * 4;
        float vs[4] = {0.f, 0.f, 0.f, 0.f};
        #pragma unroll
        for (int ni = 0; ni < 2; ++ni) {
            const int col = bcol0 + wn * 32 + ni * 16 + lr;
            const float bv = b2[col];
            #pragma unroll
            for (int r = 0; r < 4; ++r) {
                float a2 = acc1[mi][ni][r] + bv;
                float hh = tanh_fast(a2);
                float gg = 1.f - hh * hh;
                h2[(rowb + r) * 1024 + col] = f2bf(hh);
                vs[r] += acc2[mi][ni][r] * gg;
            }
        }
        #pragma unroll
        for (int off = 1; off < 16; off <<= 1)
            #pragma unroll
            for (int r = 0; r < 4; ++r)
                vs[r] += __shfl_xor(vs[r], off);
        if (lr == 0) {
            #pragma unroll
            for (int r = 0; r < 4; ++r)
                atomicAdd(&trJ[rowb + r], vs[r]);
        }
    }
}

// ---------------------------------------------------------------------------
// out: y = h2 @ W3 + b3 -> out[:,1:65];  out[:,0] = -trJ
// ---------------------------------------------------------------------------
__launch_bounds__(256)
__global__ void cnf_out(const u16* __restrict__ h2, const float* __restrict__ W3,
                        const float* __restrict__ b3, const float* __restrict__ trJ,
                        float* __restrict__ out)
{
    __shared__ __align__(16) u16 hs[8][1024];
    __shared__ float red[4][8][64];
    const int t = threadIdx.x;
    const int b0 = blockIdx.x * 8;
    #pragma unroll
    for (int it = 0; it < 4; ++it) {
        int idx = t + it * 256;
        int row = idx >> 7, ch = idx & 127;
        *(s8v*)&hs[row][ch * 8] = *(const s8v*)&h2[(b0 + row) * 1024 + ch * 8];
    }
    __syncthreads();
    const int c = t & 63, s = t >> 6;
    float acc[8] = {0.f,0.f,0.f,0.f,0.f,0.f,0.f,0.f};
    for (int k = s * 256; k < s * 256 + 256; ++k) {
        float w = W3[k * 64 + c];
        #pragma unroll
        for (int r = 0; r < 8; ++r) acc[r] += bf2f(hs[r][k]) * w;
    }
    #pragma unroll
    for (int r = 0; r < 8; ++r) red[s][r][c] = acc[r];
    __syncthreads();
    for (int o = t; o < 512; o += 256) {
        int r = o >> 6, cc = o & 63;
        float sum = red[0][r][cc] + red[1][r][cc] + red[2][r][cc] + red[3][r][cc] + b3[cc];
        out[(b0 + r) * 65 + 1 + cc] = sum;
    }
    if (t < 8) out[(b0 + t) * 65] = -trJ[b0 + t];
}

// ---------------------------------------------------------------------------
extern "C" void kernel_launch(void* const* d_in, const int* in_sizes, int n_in,
                              void* d_out, int out_size, void* d_ws, size_t ws_size,
                              hipStream_t stream) {
    const float* x  = (const float*)d_in[0];
    const float* W1 = (const float*)d_in[1];
    const float* b1 = (const float*)d_in[2];
    const float* W2 = (const float*)d_in[3];
    const float* b2 = (const float*)d_in[4];
    const float* W3 = (const float*)d_in[5];
    const float* b3 = (const float*)d_in[6];
    float* out = (float*)d_out;

    char* ws = (char*)d_ws;
    u16*   h1b = (u16*)(ws);                       //  8 MB  (4096x1024 bf16)
    u16*   g1b = (u16*)(ws + (size_t)( 8u << 20)); //  8 MB
    u16*   h2b = (u16*)(ws + (size_t)(16u << 20)); //  8 MB
    u16*   W2T = (u16*)(ws + (size_t)(24u << 20)); //  2 MB  (1024x1024 bf16, n-major)
    u16*   VTb = (u16*)(ws + (size_t)(26u << 20)); //  2 MB
    float* trJ = (float*)(ws + (size_t)(28u << 20)); // 16 KB

    cnf_prep <<<dim3(32, 32), 256, 0, stream>>>(W1, W2, W3, W2T, VTb, trJ);
    cnf_gemm1<<<2048,         256, 0, stream>>>(x, W1, b1, h1b, g1b);
    cnf_mid  <<<dim3(32, 16), 256, 0, stream>>>(h1b, g1b, W2T, VTb, b2, h2b, trJ);
    cnf_out  <<<512,          256, 0, stream>>>(h2b, W3, b3, trJ, out);
}

// Round 5
// 72.698 us; speedup vs baseline: 1.7836x; 1.5675x over previous
//
#include <hip/hip_runtime.h>
#include <cmath>

typedef unsigned short u16;
typedef __attribute__((ext_vector_type(8))) short s8v;   // 8 bf16 (4 VGPRs)
typedef __attribute__((ext_vector_type(4))) float f4v;   // MFMA accumulator / float4

__device__ __forceinline__ u16 f2bf(float f) {
    union { float f; unsigned u; } v; v.f = f;
    unsigned r = v.u + 0x7FFFu + ((v.u >> 16) & 1u);   // RNE
    return (u16)(r >> 16);
}
__device__ __forceinline__ float bf2f(u16 h) {
    union { unsigned u; float f; } v; v.u = ((unsigned)h) << 16;
    return v.f;
}
// fast tanh: 1 - 2/(1+exp2(2x*log2e)); |err| ~1e-6
__device__ __forceinline__ float tanh_fast(float x) {
    float e = __builtin_amdgcn_exp2f(x * 2.88539008177792681f);
    return 1.f - 2.f * __builtin_amdgcn_rcpf(1.f + e);
}

// Subtile layout [16 rows][64 k] bf16 = 128 slots of 16B.
// data (r, c=k/8) -> slot s = (c>>2)*64 + (c&3)*16 + r, stored at s' = s ^ ((s>>4)&7) = s ^ c.
// Reader (lane l, ks) wants slot ks*64+l -> swizzled: ks*64 + (l ^ ((ks*4+(l>>4))&7)).
// Both sides 2-lanes-per-bank-group per quarter wave (2-way = free).
__device__ __forceinline__ int wslot(int row, int c) {
    return ((((c >> 2) << 6) | ((c & 3) << 4) | (row & 15)) ^ c);
}

// ---------------------------------------------------------------------------
// prep (grid 32x32, 256 thr):
//  all blocks : W2T[n][k]=bf16(W2[k][n]); VT[q][p]=bf16(W2[p][q]*U[q][p]),
//               U = W3 @ W1 (fp32, vectorized via LDS W1 tile); xb = bf16(x[:,1:])
//  by==0      : W1T[p][i] bf16 (from LDS tile); zero trJ
//  by==1      : W3T[n][k] bf16
// ---------------------------------------------------------------------------
__launch_bounds__(256)
__global__ void cnf_prep(const float* __restrict__ x, const float* __restrict__ W1,
                         const float* __restrict__ W2, const float* __restrict__ W3,
                         u16* __restrict__ W2T, u16* __restrict__ VT,
                         u16* __restrict__ xb, u16* __restrict__ W1T,
                         u16* __restrict__ W3T, float* __restrict__ trJ)
{
    __shared__ float w2s[32][33];
    __shared__ float w1s[32][68];          // [p][i], 16B-aligned rows (68*4=272)
    const int a = blockIdx.x * 32;   // p / k rows of W2
    const int b = blockIdx.y * 32;   // q / n cols of W2
    const int t = threadIdx.x;

    #pragma unroll
    for (int it = 0; it < 4; ++it) {
        int idx = t + it * 256;
        w2s[idx >> 5][idx & 31] = W2[(a + (idx >> 5)) * 1024 + b + (idx & 31)];
    }
    #pragma unroll
    for (int it = 0; it < 8; ++it) {
        int idx = t + it * 256;
        int i = idx >> 5, pp = idx & 31;
        w1s[pp][i] = W1[i * 1024 + a + pp];
    }
    __syncthreads();

    #pragma unroll
    for (int it = 0; it < 4; ++it) {
        int idx = t + it * 256;
        int rr = idx >> 5, cc = idx & 31;
        W2T[(b + rr) * 1024 + (a + cc)] = f2bf(w2s[cc][rr]);
    }
    #pragma unroll
    for (int it = 0; it < 4; ++it) {
        int idx = t + it * 256;
        int qq = idx >> 5, pp = idx & 31;
        const float* w3row = W3 + (b + qq) * 64;
        float u = 0.f;
        #pragma unroll
        for (int i4 = 0; i4 < 16; ++i4) {
            f4v wv  = *(const f4v*)&w1s[pp][i4 * 4];
            f4v w3v = *(const f4v*)&w3row[i4 * 4];
            u += wv[0]*w3v[0] + wv[1]*w3v[1] + wv[2]*w3v[2] + wv[3]*w3v[3];
        }
        VT[(b + qq) * 1024 + (a + pp)] = f2bf(w2s[pp][qq] * u);
    }

    // xb conversion: 1024 blocks x 256 threads x 1 elem
    {
        int bid = blockIdx.y * 32 + blockIdx.x;
        int e = bid * 256 + t;
        xb[e] = f2bf(x[(e >> 6) * 65 + 1 + (e & 63)]);
    }
    if (blockIdx.y == 0) {
        int pp = t >> 3, i0 = (t & 7) * 8;
        s8v v;
        #pragma unroll
        for (int j = 0; j < 8; ++j) v[j] = (short)f2bf(w1s[pp][i0 + j]);
        *(s8v*)&W1T[(a + pp) * 64 + i0] = v;
        if (t < 128) trJ[blockIdx.x * 128 + t] = 0.f;
    }
    if (blockIdx.y == 1) {
        int idx = blockIdx.x * 256 + t;
        int n = idx & 63, k0 = (idx >> 6) * 8;
        s8v v;
        #pragma unroll
        for (int j = 0; j < 8; ++j) v[j] = (short)f2bf(W3[(k0 + j) * 64 + n]);
        *(s8v*)&W3T[n * 1024 + k0] = v;
    }
}

// ---------------------------------------------------------------------------
// zero out (4096*65 floats = 66560 float4, grid 260)
// ---------------------------------------------------------------------------
__launch_bounds__(256)
__global__ void cnf_zero(float* __restrict__ out)
{
    int i = (blockIdx.x * 256 + threadIdx.x) * 4;
    *(f4v*)&out[i] = f4v{0.f, 0.f, 0.f, 0.f};
}

// ---------------------------------------------------------------------------
// gemm1 (MFMA): h1 = tanh(xb @ W1T^T + b1), g1 = 1-h1^2
// M=4096 N=1024 K=64; tile 128x64, 4 waves 2x2, single staging.
// LDS: A = 8 subtiles, B = 4 subtiles (24 KiB).
// ---------------------------------------------------------------------------
__launch_bounds__(256)
__global__ void cnf_gemm1(const u16* __restrict__ xb, const u16* __restrict__ W1T,
                          const float* __restrict__ b1,
                          u16* __restrict__ h1, u16* __restrict__ g1)
{
    __shared__ __align__(16) u16 lds[12 * 1024];
    const int t = threadIdx.x;
    const int wave = t >> 6, lane = t & 63;
    const int wm = wave >> 1, wn = wave & 1;
    const int g = lane >> 4, lr = lane & 15;
    const int arow0 = blockIdx.x * 128, bcol0 = blockIdx.y * 64;

    #pragma unroll
    for (int i = 0; i < 4; ++i) {
        int ch = t + i * 256, row = ch >> 3, c = ch & 7;
        *(s8v*)&lds[(row >> 4) * 1024 + wslot(row, c) * 8] =
            *(const s8v*)&xb[(arow0 + row) * 64 + c * 8];
    }
    #pragma unroll
    for (int i = 0; i < 2; ++i) {
        int ch = t + i * 256, row = ch >> 3, c = ch & 7;
        *(s8v*)&lds[(8 + (row >> 4)) * 1024 + wslot(row, c) * 8] =
            *(const s8v*)&W1T[(bcol0 + row) * 64 + c * 8];
    }
    __syncthreads();

    f4v acc[4][2];
    #pragma unroll
    for (int mi = 0; mi < 4; ++mi)
        #pragma unroll
        for (int ni = 0; ni < 2; ++ni) acc[mi][ni] = f4v{0.f,0.f,0.f,0.f};

    #pragma unroll
    for (int ks = 0; ks < 2; ++ks) {
        const int lo = (ks * 64 + (lane ^ ((ks * 4 + g) & 7))) * 8;
        s8v af[4], bf[2];
        #pragma unroll
        for (int mi = 0; mi < 4; ++mi) af[mi] = *(const s8v*)&lds[(wm * 4 + mi) * 1024 + lo];
        #pragma unroll
        for (int ni = 0; ni < 2; ++ni) bf[ni] = *(const s8v*)&lds[(8 + wn * 2 + ni) * 1024 + lo];
        #pragma unroll
        for (int mi = 0; mi < 4; ++mi)
            #pragma unroll
            for (int ni = 0; ni < 2; ++ni)
                acc[mi][ni] = __builtin_amdgcn_mfma_f32_16x16x32_bf16(af[mi], bf[ni], acc[mi][ni], 0, 0, 0);
    }

    #pragma unroll
    for (int mi = 0; mi < 4; ++mi) {
        const int rowb = arow0 + wm * 64 + mi * 16 + g * 4;
        #pragma unroll
        for (int ni = 0; ni < 2; ++ni) {
            const int col = bcol0 + wn * 32 + ni * 16 + lr;
            const float bv = b1[col];
            #pragma unroll
            for (int r = 0; r < 4; ++r) {
                float h = tanh_fast(acc[mi][ni][r] + bv);
                h1[(rowb + r) * 1024 + col] = f2bf(h);
                g1[(rowb + r) * 1024 + col] = f2bf(1.f - h * h);
            }
        }
    }
}

// ---------------------------------------------------------------------------
// mid: fused dual GEMM over K=1024 (tile 128x64, BK=64, 16 iters, 4 waves 2x2)
//   C2 = h1 @ W2  -> h2 = tanh(C2+b2) (bf16), g2 in reg
//   T  = g1 @ V   -> trJ[row] += sum_col T*g2
// LDS: 24 subtiles (A1:0-7, A2:8-15, B1:16-19, B2:20-23) = 48 KiB, single buf.
// ---------------------------------------------------------------------------
__launch_bounds__(256)
__global__ void cnf_mid(const u16* __restrict__ h1, const u16* __restrict__ g1,
                        const u16* __restrict__ W2T, const u16* __restrict__ VT,
                        const float* __restrict__ b2,
                        u16* __restrict__ h2, float* __restrict__ trJ)
{
    __shared__ __align__(16) u16 lds[24 * 1024];
    const int t = threadIdx.x;
    const int wave = t >> 6, lane = t & 63;
    const int wm = wave >> 1, wn = wave & 1;
    const int g = lane >> 4, lr = lane & 15;
    const int arow0 = blockIdx.x * 128;
    const int bcol0 = blockIdx.y * 64;

    // staging plan: 12 chunks/thread (A1 x4, A2 x4, B1 x2, B2 x2)
    const u16* sp[12]; int dp[12];
    #pragma unroll
    for (int i = 0; i < 4; ++i) {
        int ch = t + i * 256, row = ch >> 3, c = ch & 7;
        int d = (row >> 4) * 1024 + wslot(row, c) * 8;
        sp[i]     = h1 + (size_t)(arow0 + row) * 1024 + c * 8;  dp[i]     = d;
        sp[4 + i] = g1 + (size_t)(arow0 + row) * 1024 + c * 8;  dp[4 + i] = d + 8 * 1024;
    }
    #pragma unroll
    for (int i = 0; i < 2; ++i) {
        int ch = t + i * 256, row = ch >> 3, c = ch & 7;
        int d = (row >> 4) * 1024 + wslot(row, c) * 8;
        sp[8 + i]  = W2T + (size_t)(bcol0 + row) * 1024 + c * 8;  dp[8 + i]  = d + 16 * 1024;
        sp[10 + i] = VT  + (size_t)(bcol0 + row) * 1024 + c * 8;  dp[10 + i] = d + 20 * 1024;
    }

    f4v acc1[4][2], acc2[4][2];
    #pragma unroll
    for (int mi = 0; mi < 4; ++mi)
        #pragma unroll
        for (int ni = 0; ni < 2; ++ni) {
            acc1[mi][ni] = f4v{0.f,0.f,0.f,0.f};
            acc2[mi][ni] = f4v{0.f,0.f,0.f,0.f};
        }

    for (int kt = 0; kt < 16; ++kt) {
        s8v rg[12];
        #pragma unroll
        for (int i = 0; i < 12; ++i) rg[i] = *(const s8v*)(sp[i] + kt * 64);
        #pragma unroll
        for (int i = 0; i < 12; ++i) *(s8v*)&lds[dp[i]] = rg[i];
        __syncthreads();

        #pragma unroll
        for (int ks = 0; ks < 2; ++ks) {
            const int lo = (ks * 64 + (lane ^ ((ks * 4 + g) & 7))) * 8;
            s8v a1[4], a2[4], b1f[2], b2f[2];
            #pragma unroll
            for (int mi = 0; mi < 4; ++mi) {
                a1[mi] = *(const s8v*)&lds[(wm * 4 + mi) * 1024 + lo];
                a2[mi] = *(const s8v*)&lds[(8 + wm * 4 + mi) * 1024 + lo];
            }
            #pragma unroll
            for (int ni = 0; ni < 2; ++ni) {
                b1f[ni] = *(const s8v*)&lds[(16 + wn * 2 + ni) * 1024 + lo];
                b2f[ni] = *(const s8v*)&lds[(20 + wn * 2 + ni) * 1024 + lo];
            }
            #pragma unroll
            for (int mi = 0; mi < 4; ++mi)
                #pragma unroll
                for (int ni = 0; ni < 2; ++ni) {
                    acc1[mi][ni] = __builtin_amdgcn_mfma_f32_16x16x32_bf16(a1[mi], b1f[ni], acc1[mi][ni], 0, 0, 0);
                    acc2[mi][ni] = __builtin_amdgcn_mfma_f32_16x16x32_bf16(a2[mi], b2f[ni], acc2[mi][ni], 0, 0, 0);
                }
        }
        __syncthreads();
    }

    // epilogue: h2/g2 + trace partial reduction
    #pragma unroll
    for (int mi = 0; mi < 4; ++mi) {
        const int rowb = arow0 + wm * 64 + mi * 16 + g * 4;
        float vs[4] = {0.f, 0.f, 0.f, 0.f};
        #pragma unroll
        for (int ni = 0; ni < 2; ++ni) {
            const int col = bcol0 + wn * 32 + ni * 16 + lr;
            const float bv = b2[col];
            #pragma unroll
            for (int r = 0; r < 4; ++r) {
                float hh = tanh_fast(acc1[mi][ni][r] + bv);
                float gg = 1.f - hh * hh;
                h2[(rowb + r) * 1024 + col] = f2bf(hh);
                vs[r] += acc2[mi][ni][r] * gg;
            }
        }
        #pragma unroll
        for (int off = 1; off < 16; off <<= 1)
            #pragma unroll
            for (int r = 0; r < 4; ++r)
                vs[r] += __shfl_xor(vs[r], off);
        if (lr == 0) {
            #pragma unroll
            for (int r = 0; r < 4; ++r)
                atomicAdd(&trJ[rowb + r], vs[r]);
        }
    }
}

// ---------------------------------------------------------------------------
// out (MFMA, K-split): y = h2 @ W3T^T + b3 -> atomicAdd into out[:,1:65]
// grid (64, 4): 64-row tiles x 4 K-chunks of 256. 4 waves 2x2, tile 64x64.
// LDS: A 16 subtiles + B 16 subtiles = 64 KiB. kq==0 also writes out[:,0]=-trJ.
// ---------------------------------------------------------------------------
__launch_bounds__(256)
__global__ void cnf_out(const u16* __restrict__ h2, const u16* __restrict__ W3T,
                        const float* __restrict__ b3, const float* __restrict__ trJ,
                        float* __restrict__ out)
{
    __shared__ __align__(16) u16 lds[32 * 1024];
    const int t = threadIdx.x;
    const int wave = t >> 6, lane = t & 63;
    const int wm = wave >> 1, wn = wave & 1;
    const int g = lane >> 4, lr = lane & 15;
    const int r0 = blockIdx.x * 64;
    const int kq = blockIdx.y;
    const int kbase = kq * 256;

    #pragma unroll
    for (int i = 0; i < 8; ++i) {
        int ch = t + i * 256, row = ch >> 5, c = ch & 31, cc = c & 7, kg = c >> 3;
        int d = (kg * 4 + (row >> 4)) * 1024 + wslot(row, cc) * 8;
        *(s8v*)&lds[d]             = *(const s8v*)&h2[(size_t)(r0 + row) * 1024 + kbase + c * 8];
        *(s8v*)&lds[d + 16 * 1024] = *(const s8v*)&W3T[(size_t)row * 1024 + kbase + c * 8];
    }
    __syncthreads();

    f4v acc[2][2];
    #pragma unroll
    for (int mi = 0; mi < 2; ++mi)
        #pragma unroll
        for (int ni = 0; ni < 2; ++ni) acc[mi][ni] = f4v{0.f,0.f,0.f,0.f};

    #pragma unroll
    for (int j = 0; j < 8; ++j) {
        const int kg = j >> 1, ks = j & 1;
        const int lo = (ks * 64 + (lane ^ ((ks * 4 + g) & 7))) * 8;
        s8v af[2], bf[2];
        #pragma unroll
        for (int mi = 0; mi < 2; ++mi) af[mi] = *(const s8v*)&lds[(kg * 4 + wm * 2 + mi) * 1024 + lo];
        #pragma unroll
        for (int ni = 0; ni < 2; ++ni) bf[ni] = *(const s8v*)&lds[(16 + kg * 4 + wn * 2 + ni) * 1024 + lo];
        #pragma unroll
        for (int mi = 0; mi < 2; ++mi)
            #pragma unroll
            for (int ni = 0; ni < 2; ++ni)
                acc[mi][ni] = __builtin_amdgcn_mfma_f32_16x16x32_bf16(af[mi], bf[ni], acc[mi][ni], 0, 0, 0);
    }

    #pragma unroll
    for (int mi = 0; mi < 2; ++mi) {
        const int rowb = r0 + wm * 32 + mi * 16 + g * 4;
        #pragma unroll
        for (int ni = 0; ni < 2; ++ni) {
            const int col = wn * 32 + ni * 16 + lr;
            const float bv = (kq == 0) ? b3[col] : 0.f;
            #pragma unroll
            for (int r = 0; r < 4; ++r)
                atomicAdd(&out[(size_t)(rowb + r) * 65 + 1 + col], acc[mi][ni][r] + bv);
        }
    }
    if (kq == 0 && t < 64) out[(size_t)(r0 + t) * 65] = -trJ[r0 + t];
}

// ---------------------------------------------------------------------------
extern "C" void kernel_launch(void* const* d_in, const int* in_sizes, int n_in,
                              void* d_out, int out_size, void* d_ws, size_t ws_size,
                              hipStream_t stream) {
    const float* x  = (const float*)d_in[0];
    const float* W1 = (const float*)d_in[1];
    const float* b1 = (const float*)d_in[2];
    const float* W2 = (const float*)d_in[3];
    const float* b2 = (const float*)d_in[4];
    const float* W3 = (const float*)d_in[5];
    const float* b3 = (const float*)d_in[6];
    float* out = (float*)d_out;

    char* ws = (char*)d_ws;
    u16*   h1b = (u16*)(ws);                                  //  8 MB
    u16*   g1b = (u16*)(ws + (size_t)( 8u << 20));            //  8 MB
    u16*   h2b = (u16*)(ws + (size_t)(16u << 20));            //  8 MB
    u16*   W2T = (u16*)(ws + (size_t)(24u << 20));            //  2 MB
    u16*   VTb = (u16*)(ws + (size_t)(26u << 20));            //  2 MB
    float* trJ = (float*)(ws + (size_t)(28u << 20));          // 16 KB
    u16*   xbb = (u16*)(ws + (size_t)(28u << 20) + 65536);    // 512 KB
    u16*   W1T = (u16*)(ws + (size_t)(28u << 20) + 65536 + 524288);   // 128 KB
    u16*   W3T = (u16*)(ws + (size_t)(28u << 20) + 65536 + 524288 + 131072); // 128 KB

    cnf_prep <<<dim3(32, 32), 256, 0, stream>>>(x, W1, W2, W3, W2T, VTb, xbb, W1T, W3T, trJ);
    cnf_zero <<<260,          256, 0, stream>>>(out);
    cnf_gemm1<<<dim3(32, 16), 256, 0, stream>>>(xbb, W1T, b1, h1b, g1b);
    cnf_mid  <<<dim3(32, 16), 256, 0, stream>>>(h1b, g1b, W2T, VTb, b2, h2b, trJ);
    cnf_out  <<<dim3(64, 4),  256, 0, stream>>>(h2b, W3T, b3, trJ, out);
}

// Round 6
// 61.287 us; speedup vs baseline: 2.1157x; 1.1862x over previous
//
#include <hip/hip_runtime.h>
#include <cmath>

typedef unsigned short u16;
typedef __attribute__((ext_vector_type(8))) short s8v;    // 8 bf16 (4 VGPRs)
typedef __attribute__((ext_vector_type(4))) float f4v;    // 16x16 acc / float4
typedef __attribute__((ext_vector_type(16))) float f16v;  // 32x32 acc

__device__ __forceinline__ u16 f2bf(float f) {
    union { float f; unsigned u; } v; v.f = f;
    unsigned r = v.u + 0x7FFFu + ((v.u >> 16) & 1u);   // RNE
    return (u16)(r >> 16);
}
// fast tanh: 1 - 2/(1+exp2(2x*log2e)); |err| ~1e-6
__device__ __forceinline__ float tanh_fast(float x) {
    float e = __builtin_amdgcn_exp2f(x * 2.88539008177792681f);
    return 1.f - 2.f * __builtin_amdgcn_rcpf(1.f + e);
}
// 16x16 subtile swizzled slot (gemm1 only; verified R5)
__device__ __forceinline__ int wslot(int row, int c) {
    return ((((c >> 2) << 6) | ((c & 3) << 4) | (row & 15)) ^ c);
}
// fragment-layout flat u16 index for element (n,k) of an n-major matrix:
// frag tile nt=n>>5, kk=k>>4; lane = (n&31) + ((k>>3)&1)*32; j = k&7
__device__ __forceinline__ size_t fragoff(int n, int k) {
    return (((size_t)(n >> 5) * 64 + (k >> 4)) * 64 + (n & 31) + (((k >> 3) & 1) << 5)) * 8 + (k & 7);
}

// ---------------------------------------------------------------------------
// prep (grid 32x32, 256 thr):
//  all blocks : W2Tf[frag(n,k)]=bf16(W2[k][n]); VTf[frag(q,p)]=bf16(W2[p][q]*U[q][p]),
//               U = W3 @ W1 ; xb = bf16(x[:,1:])
//  by==0      : W1T[p][i] bf16 row-major; zero trJ
//  by==1      : W3Tf[frag(n,k)] = bf16(W3[k][n])
// ---------------------------------------------------------------------------
__launch_bounds__(256)
__global__ void cnf_prep(const float* __restrict__ x, const float* __restrict__ W1,
                         const float* __restrict__ W2, const float* __restrict__ W3,
                         u16* __restrict__ W2Tf, u16* __restrict__ VTf,
                         u16* __restrict__ xb, u16* __restrict__ W1T,
                         u16* __restrict__ W3Tf, float* __restrict__ trJ)
{
    __shared__ float w2s[32][33];
    __shared__ float w1s[32][68];
    const int a = blockIdx.x * 32;   // p / k (rows of W2)
    const int b = blockIdx.y * 32;   // q / n (cols of W2)
    const int t = threadIdx.x;

    #pragma unroll
    for (int it = 0; it < 4; ++it) {
        int idx = t + it * 256;
        w2s[idx >> 5][idx & 31] = W2[(a + (idx >> 5)) * 1024 + b + (idx & 31)];
    }
    #pragma unroll
    for (int it = 0; it < 8; ++it) {
        int idx = t + it * 256;
        w1s[idx & 31][idx >> 5] = W1[(idx >> 5) * 1024 + a + (idx & 31)];
    }
    __syncthreads();

    #pragma unroll
    for (int it = 0; it < 4; ++it) {
        int idx = t + it * 256;
        int rr = idx >> 5, cc = idx & 31;
        W2Tf[fragoff(b + rr, a + cc)] = f2bf(w2s[cc][rr]);
    }
    #pragma unroll
    for (int it = 0; it < 4; ++it) {
        int idx = t + it * 256;
        int qq = idx >> 5, pp = idx & 31;
        const float* w3row = W3 + (b + qq) * 64;
        float u = 0.f;
        #pragma unroll
        for (int i4 = 0; i4 < 16; ++i4) {
            f4v wv  = *(const f4v*)&w1s[pp][i4 * 4];
            f4v w3v = *(const f4v*)&w3row[i4 * 4];
            u += wv[0]*w3v[0] + wv[1]*w3v[1] + wv[2]*w3v[2] + wv[3]*w3v[3];
        }
        VTf[fragoff(b + qq, a + pp)] = f2bf(w2s[pp][qq] * u);
    }
    {
        int bid = blockIdx.y * 32 + blockIdx.x;
        int e = bid * 256 + t;
        xb[e] = f2bf(x[(e >> 6) * 65 + 1 + (e & 63)]);
    }
    if (blockIdx.y == 0) {
        int pp = t >> 3, i0 = (t & 7) * 8;
        s8v v;
        #pragma unroll
        for (int j = 0; j < 8; ++j) v[j] = (short)f2bf(w1s[pp][i0 + j]);
        *(s8v*)&W1T[(a + pp) * 64 + i0] = v;
        if (t < 128) trJ[blockIdx.x * 128 + t] = 0.f;
    }
    if (blockIdx.y == 1) {
        int idx = blockIdx.x * 256 + t;
        int n = idx & 63, k0 = (idx >> 6) * 8;
        s8v v;
        #pragma unroll
        for (int j = 0; j < 8; ++j) v[j] = (short)f2bf(W3[(k0 + j) * 64 + n]);
        *(s8v*)&W3Tf[fragoff(n, k0)] = v;
    }
}

// ---------------------------------------------------------------------------
// gemm1 (MFMA 16x16x32): h1 = tanh(xb @ W1T^T + b1), g1 = 1-h1^2  (row-major out)
// ---------------------------------------------------------------------------
__launch_bounds__(256)
__global__ void cnf_gemm1(const u16* __restrict__ xb, const u16* __restrict__ W1T,
                          const float* __restrict__ b1,
                          u16* __restrict__ h1, u16* __restrict__ g1)
{
    __shared__ __align__(16) u16 lds[12 * 1024];
    const int t = threadIdx.x;
    const int wave = t >> 6, lane = t & 63;
    const int wm = wave >> 1, wn = wave & 1;
    const int g = lane >> 4, lr = lane & 15;
    const int arow0 = blockIdx.x * 128, bcol0 = blockIdx.y * 64;

    #pragma unroll
    for (int i = 0; i < 4; ++i) {
        int ch = t + i * 256, row = ch >> 3, c = ch & 7;
        *(s8v*)&lds[(row >> 4) * 1024 + wslot(row, c) * 8] =
            *(const s8v*)&xb[(arow0 + row) * 64 + c * 8];
    }
    #pragma unroll
    for (int i = 0; i < 2; ++i) {
        int ch = t + i * 256, row = ch >> 3, c = ch & 7;
        *(s8v*)&lds[(8 + (row >> 4)) * 1024 + wslot(row, c) * 8] =
            *(const s8v*)&W1T[(bcol0 + row) * 64 + c * 8];
    }
    __syncthreads();

    f4v acc[4][2];
    #pragma unroll
    for (int mi = 0; mi < 4; ++mi)
        #pragma unroll
        for (int ni = 0; ni < 2; ++ni) acc[mi][ni] = f4v{0.f,0.f,0.f,0.f};

    #pragma unroll
    for (int ks = 0; ks < 2; ++ks) {
        const int lo = (ks * 64 + (lane ^ ((ks * 4 + g) & 7))) * 8;
        s8v af[4], bf[2];
        #pragma unroll
        for (int mi = 0; mi < 4; ++mi) af[mi] = *(const s8v*)&lds[(wm * 4 + mi) * 1024 + lo];
        #pragma unroll
        for (int ni = 0; ni < 2; ++ni) bf[ni] = *(const s8v*)&lds[(8 + wn * 2 + ni) * 1024 + lo];
        #pragma unroll
        for (int mi = 0; mi < 4; ++mi)
            #pragma unroll
            for (int ni = 0; ni < 2; ++ni)
                acc[mi][ni] = __builtin_amdgcn_mfma_f32_16x16x32_bf16(af[mi], bf[ni], acc[mi][ni], 0, 0, 0);
    }

    #pragma unroll
    for (int mi = 0; mi < 4; ++mi) {
        const int rowb = arow0 + wm * 64 + mi * 16 + g * 4;
        #pragma unroll
        for (int ni = 0; ni < 2; ++ni) {
            const int col = bcol0 + wn * 32 + ni * 16 + lr;
            const float bv = b1[col];
            #pragma unroll
            for (int r = 0; r < 4; ++r) {
                float h = tanh_fast(acc[mi][ni][r] + bv);
                h1[(rowb + r) * 1024 + col] = f2bf(h);
                g1[(rowb + r) * 1024 + col] = f2bf(1.f - h * h);
            }
        }
    }
}

// ---------------------------------------------------------------------------
// mid: fused dual GEMM, K=1024, tile 128x128, 4 waves 2x2 (wave 64x64),
// mfma_f32_32x32x16_bf16. A (h1,g1) LDS ping-pong (1 barrier/kt, swizzled);
// B (W2Tf,VTf) direct global fragment loads, double-buffered 1 kt ahead.
//   C2 = h1@W2 -> h2f (fragment layout, bf16); T = g1@V -> trJ += rowsum(T*g2)
// ---------------------------------------------------------------------------
#define LOADA(d0, d1, d2, d3, ko)                                              \
    do { d0 = *(const s8v*)(h1p0 + (ko)); d1 = *(const s8v*)(h1p1 + (ko));     \
         d2 = *(const s8v*)(g1p0 + (ko)); d3 = *(const s8v*)(g1p1 + (ko)); } while (0)

#define LOADB(B, kkg)                                                          \
    do { _Pragma("unroll")                                                     \
         for (int _ks = 0; _ks < 2; ++_ks)                                     \
         _Pragma("unroll")                                                     \
         for (int _ni = 0; _ni < 2; ++_ni) {                                   \
             size_t _o = (((size_t)(ntb + wn * 2 + _ni) * 64 + (kkg)*2 + _ks) * 64 + lane) * 8; \
             B[_ks*4 + _ni*2 + 0] = *(const s8v*)&W2Tf[_o];                    \
             B[_ks*4 + _ni*2 + 1] = *(const s8v*)&VTf[_o];                     \
         } } while (0)

#define WRITEA(s0, s1, s2, s3, bb)                                             \
    do { u16* _wb = &lds[bb][0];                                               \
         *(s8v*)&_wb[sdst0] = s0; *(s8v*)&_wb[sdst1] = s1;                     \
         *(s8v*)&_wb[4096 + sdst0] = s2; *(s8v*)&_wb[4096 + sdst1] = s3; } while (0)

#define MIDBODY(kt, Aw0, Aw1, Aw2, Aw3, Al0, Al1, Al2, Al3, Bc, Bn)            \
    {                                                                          \
        if ((kt) < 30) { const int _ko = ((kt) + 2) * 32;                      \
                         LOADA(Al0, Al1, Al2, Al3, _ko); }                     \
        if ((kt) < 31) { WRITEA(Aw0, Aw1, Aw2, Aw3, ((kt) + 1) & 1);           \
                         LOADB(Bn, (kt) + 1); }                                \
        const u16* buf = &lds[(kt) & 1][0];                                    \
        _Pragma("unroll")                                                      \
        for (int ks = 0; ks < 2; ++ks) {                                       \
            const int lp = (lane ^ ((lane >> 5) << 2) ^ (ks << 1)) * 8;        \
            s8v af1[2], af2[2];                                                \
            _Pragma("unroll")                                                  \
            for (int mi = 0; mi < 2; ++mi) {                                   \
                int R = (wm * 2 + mi) * 2 + ks;                                \
                af1[mi] = *(const s8v*)&buf[R * 512 + lp];                     \
                af2[mi] = *(const s8v*)&buf[4096 + R * 512 + lp];              \
            }                                                                  \
            _Pragma("unroll")                                                  \
            for (int mi = 0; mi < 2; ++mi)                                     \
                _Pragma("unroll")                                              \
                for (int ni = 0; ni < 2; ++ni) {                               \
                    acc1[mi][ni] = __builtin_amdgcn_mfma_f32_32x32x16_bf16(af1[mi], Bc[ks*4+ni*2+0], acc1[mi][ni], 0, 0, 0); \
                    acc2[mi][ni] = __builtin_amdgcn_mfma_f32_32x32x16_bf16(af2[mi], Bc[ks*4+ni*2+1], acc2[mi][ni], 0, 0, 0); \
                }                                                              \
        }                                                                      \
        __syncthreads();                                                       \
    }

__launch_bounds__(256, 1)
__global__ void cnf_mid(const u16* __restrict__ h1, const u16* __restrict__ g1,
                        const u16* __restrict__ W2Tf, const u16* __restrict__ VTf,
                        const float* __restrict__ b2,
                        u16* __restrict__ h2f, float* __restrict__ trJ)
{
    __shared__ __align__(16) u16 lds[2][8192];   // 2 x 16 KiB

    const int t = threadIdx.x;
    const int wave = t >> 6, lane = t & 63;
    const int wm = wave >> 1, wn = wave & 1;
    const int arow0 = blockIdx.x * 128;
    const int ntb = blockIdx.y * 4;

    // staging geometry: 2 chunks/thread/matrix; chunk = (row, k-chunk c of 8)
    const int row0 = t >> 2,        c0 = t & 3;
    const int row1 = (t + 256) >> 2, c1 = t & 3;
    int R0 = (row0 >> 5) * 2 + (c0 >> 1), L0 = (row0 & 31) + ((c0 & 1) << 5);
    int R1 = (row1 >> 5) * 2 + (c1 >> 1), L1 = (row1 & 31) + ((c1 & 1) << 5);
    const int sdst0 = (R0 * 64 + (L0 ^ ((L0 >> 5) << 2) ^ ((R0 & 1) << 1))) * 8;
    const int sdst1 = (R1 * 64 + (L1 ^ ((L1 >> 5) << 2) ^ ((R1 & 1) << 1))) * 8;
    const u16* h1p0 = h1 + (size_t)(arow0 + row0) * 1024 + c0 * 8;
    const u16* h1p1 = h1 + (size_t)(arow0 + row1) * 1024 + c1 * 8;
    const u16* g1p0 = g1 + (size_t)(arow0 + row0) * 1024 + c0 * 8;
    const u16* g1p1 = g1 + (size_t)(arow0 + row1) * 1024 + c1 * 8;

    f16v acc1[2][2], acc2[2][2];
    #pragma unroll
    for (int mi = 0; mi < 2; ++mi)
        #pragma unroll
        for (int ni = 0; ni < 2; ++ni) {
            #pragma unroll
            for (int r = 0; r < 16; ++r) { acc1[mi][ni][r] = 0.f; acc2[mi][ni][r] = 0.f; }
        }

    s8v aA0, aA1, aA2, aA3, aB0, aB1, aB2, aB3;
    s8v bA[8], bB[8];

    LOADA(aA0, aA1, aA2, aA3, 0);          // A(0)
    WRITEA(aA0, aA1, aA2, aA3, 0);         // -> lds[0]
    LOADA(aB0, aB1, aB2, aB3, 32);         // A(1)
    LOADB(bA, 0);                          // B(0)
    __syncthreads();

    for (int kt2 = 0; kt2 < 16; ++kt2) {
        const int kt = kt2 * 2;
        MIDBODY(kt,     aB0, aB1, aB2, aB3, aA0, aA1, aA2, aA3, bA, bB);
        MIDBODY(kt + 1, aA0, aA1, aA2, aA3, aB0, aB1, aB2, aB3, bB, bA);
    }

    // epilogue: h2 (frag layout) + trace reduction
    const int l31 = lane & 31, lh = lane >> 5;
    #pragma unroll
    for (int mi = 0; mi < 2; ++mi) {
        const int rt = (arow0 >> 5) + wm * 2 + mi;
        float tr[16];
        #pragma unroll
        for (int r = 0; r < 16; ++r) tr[r] = 0.f;
        #pragma unroll
        for (int ni = 0; ni < 2; ++ni) {
            const int q0 = (ntb + wn * 2 + ni) * 32;       // col base; col = q0 + l31
            const float bv = b2[q0 + l31];
            const size_t hb = (((size_t)rt * 64 + ((q0 + l31) >> 4)) * 64
                               + (((l31 >> 3) & 1) << 5)) * 8 + (l31 & 7) + lh * 32;
            #pragma unroll
            for (int r = 0; r < 16; ++r) {
                float hh = tanh_fast(acc1[mi][ni][r] + bv);
                float gg = 1.f - hh * hh;
                h2f[hb + ((r & 3) + ((r >> 2) << 3)) * 8] = f2bf(hh);
                tr[r] += acc2[mi][ni][r] * gg;
            }
        }
        #pragma unroll
        for (int off = 1; off < 32; off <<= 1)
            #pragma unroll
            for (int r = 0; r < 16; ++r) tr[r] += __shfl_xor(tr[r], off);
        if (l31 == 0) {
            const int rowb = arow0 + wm * 64 + mi * 32 + lh * 4;
            #pragma unroll
            for (int r = 0; r < 16; ++r)
                atomicAdd(&trJ[rowb + (r & 3) + ((r >> 2) << 3)], tr[r]);
        }
    }
}

// ---------------------------------------------------------------------------
// out: y = h2 @ W3 + b3 (fragment-direct, wave-split K, LDS reduce; no atomics)
// grid 128: 32-row tiles. out[:,0] = -trJ.
// ---------------------------------------------------------------------------
__launch_bounds__(256)
__global__ void cnf_out(const u16* __restrict__ h2f, const u16* __restrict__ W3Tf,
                        const float* __restrict__ b3, const float* __restrict__ trJ,
                        float* __restrict__ out)
{
    __shared__ float red[4][32][64];
    const int t = threadIdx.x;
    const int wave = t >> 6, lane = t & 63;
    const int rt = blockIdx.x;

    f16v acc[2];
    #pragma unroll
    for (int ni = 0; ni < 2; ++ni)
        #pragma unroll
        for (int r = 0; r < 16; ++r) acc[ni][r] = 0.f;

    #pragma unroll
    for (int kki = 0; kki < 16; ++kki) {
        const int kk = wave * 16 + kki;
        s8v af = *(const s8v*)&h2f[(((size_t)rt * 64 + kk) * 64 + lane) * 8];
        #pragma unroll
        for (int ni = 0; ni < 2; ++ni) {
            s8v bf = *(const s8v*)&W3Tf[(((size_t)ni * 64 + kk) * 64 + lane) * 8];
            acc[ni] = __builtin_amdgcn_mfma_f32_32x32x16_bf16(af, bf, acc[ni], 0, 0, 0);
        }
    }
    const int l31 = lane & 31, lh = lane >> 5;
    #pragma unroll
    for (int ni = 0; ni < 2; ++ni)
        #pragma unroll
        for (int r = 0; r < 16; ++r)
            red[wave][(r & 3) + ((r >> 2) << 3) + lh * 4][ni * 32 + l31] = acc[ni][r];
    __syncthreads();

    #pragma unroll
    for (int i = 0; i < 8; ++i) {
        int o = t * 8 + i;
        int row = o >> 6, col = o & 63;
        float s = red[0][row][col] + red[1][row][col] + red[2][row][col] + red[3][row][col] + b3[col];
        out[(size_t)(rt * 32 + row) * 65 + 1 + col] = s;
    }
    if (t < 32) out[(size_t)(rt * 32 + t) * 65] = -trJ[rt * 32 + t];
}

// ---------------------------------------------------------------------------
extern "C" void kernel_launch(void* const* d_in, const int* in_sizes, int n_in,
                              void* d_out, int out_size, void* d_ws, size_t ws_size,
                              hipStream_t stream) {
    const float* x  = (const float*)d_in[0];
    const float* W1 = (const float*)d_in[1];
    const float* b1 = (const float*)d_in[2];
    const float* W2 = (const float*)d_in[3];
    const float* b2 = (const float*)d_in[4];
    const float* W3 = (const float*)d_in[5];
    const float* b3 = (const float*)d_in[6];
    float* out = (float*)d_out;

    char* ws = (char*)d_ws;
    u16*   h1b = (u16*)(ws);                                  //  8 MB
    u16*   g1b = (u16*)(ws + (size_t)( 8u << 20));            //  8 MB
    u16*   h2f = (u16*)(ws + (size_t)(16u << 20));            //  8 MB (frag layout)
    u16*   W2T = (u16*)(ws + (size_t)(24u << 20));            //  2 MB (frag layout)
    u16*   VTb = (u16*)(ws + (size_t)(26u << 20));            //  2 MB (frag layout)
    float* trJ = (float*)(ws + (size_t)(28u << 20));          // 16 KB
    u16*   xbb = (u16*)(ws + (size_t)(28u << 20) + 65536);    // 512 KB
    u16*   W1T = (u16*)(ws + (size_t)(28u << 20) + 65536 + 524288);             // 128 KB
    u16*   W3T = (u16*)(ws + (size_t)(28u << 20) + 65536 + 524288 + 131072);    // 128 KB (frag)

    cnf_prep <<<dim3(32, 32), 256, 0, stream>>>(x, W1, W2, W3, W2T, VTb, xbb, W1T, W3T, trJ);
    cnf_gemm1<<<dim3(32, 16), 256, 0, stream>>>(xbb, W1T, b1, h1b, g1b);
    cnf_mid  <<<dim3(32, 8),  256, 0, stream>>>(h1b, g1b, W2T, VTb, b2, h2f, trJ);
    cnf_out  <<<128,          256, 0, stream>>>(h2f, W3T, b3, trJ, out);
}